// Round 6
// baseline (388.401 us; speedup 1.0000x reference)
//
#include <hip/hip_runtime.h>
#include <cfloat>
#include <cmath>

#define N_TOK (32*4096)                 // 131072 tokens
#define DIM   64
#define N_E   1024

typedef __attribute__((ext_vector_type(8))) __bf16 bf16x8;
typedef __attribute__((ext_vector_type(4))) float  f32x4;
typedef unsigned int u32;

// ws layout (bytes)
#define WS_CN2    0u                    // 1024 f32 (-0.5*||e||^2)            (4 KB)
#define WS_CBF    4096u                 // chunk-major bf16: hi 128KB + lo 128KB
#define WS_COUNTS 266240u               // 1024 u32
#define WS_SSE    270336u               // 1 f32
#define WS_DONE   270340u               // 1 u32

// Codebook -> chunk-major MFMA B-fragment order. Chunk c (16 codes), lane (q,n):
//   cbF[c*1024 + kf*512 + (q*16+n)*8 + j] = hi( e[c*16+n][kf*32 + q*8 + j] )
// lo plane at +65536 elems. K-loop load is then ptr + lane*8, advancing 1024/chunk.
__global__ __launch_bounds__(256) void prep_kernel(const float* __restrict__ cb,
        float* __restrict__ cn2, __bf16* __restrict__ cbF,
        unsigned* __restrict__ counts, float* __restrict__ sse, unsigned* __restrict__ done) {
    int k = blockIdx.x * 256 + threadIdx.x;          // 0..1023
    counts[k] = 0u;
    if (k == 0) { *sse = 0.f; *done = 0u; }
    const float* row = cb + (size_t)k * DIM;
    const int c = k >> 4, n = k & 15;
    __bf16* bh = cbF + (size_t)c * 1024 + n * 8;
    __bf16* bl = bh + 65536;
    float nrm = 0.f;
#pragma unroll
    for (int kf = 0; kf < 2; ++kf) {
#pragma unroll
        for (int q = 0; q < 4; ++q) {
            float4 a = *(const float4*)(row + kf*32 + q*8);
            float4 b = *(const float4*)(row + kf*32 + q*8 + 4);
            float v[8] = {a.x,a.y,a.z,a.w,b.x,b.y,b.z,b.w};
            bf16x8 hv, lv;
#pragma unroll
            for (int j = 0; j < 8; ++j) {
                float f = v[j];
                nrm = fmaf(f, f, nrm);
                __bf16 h = (__bf16)f;
                __bf16 l = (__bf16)(f - (float)h);
                hv[j] = h; lv[j] = l;
            }
            *(bf16x8*)(bh + kf*512 + q*128) = hv;
            *(bf16x8*)(bl + kf*512 + q*128) = lv;
        }
    }
    cn2[k] = -0.5f * nrm;
}

// Split-K fused kernel: block = 4 waves over 64 tokens; wave w scans codebook
// quarter [w*256, w*256+256). Barrier-free K-loop (B direct from L2-resident cbF).
// One LDS merge, then per-wave counts/SSE/z_q for its 16 tokens. Last block
// computes loss/perplexity (device-scope atomic handshake).
__global__ __launch_bounds__(256, 4) void fused_kernel(const float* __restrict__ z,
        const __bf16* __restrict__ cbF, const float* __restrict__ cn2,
        const float* __restrict__ cb, float* __restrict__ out,
        unsigned* __restrict__ counts, float* __restrict__ sse, unsigned* __restrict__ done) {
    __shared__ float lmerge[256];                    // [wave][token0..63] packed winners
    __shared__ float fred[4];
    __shared__ u32 lastflag;
    const int t    = threadIdx.x;
    const int lane = t & 63;
    const int w    = t >> 6;
    const int n    = lane & 15;                      // MFMA col / code-in-chunk
    const int q    = lane >> 4;                      // k-octet selector
    const int wtok = blockIdx.x * 64;

    // A fragments: ALL 64 block-tokens per wave (same addrs across waves -> L1 reuse).
    // pn[tile] = exact fp32 ||z||^2 of token wtok+tile*16+n (after q-reduce).
    bf16x8 ah[4][2], al[4][2];
    float pn[4];
    const float4* z4 = (const float4*)z;
#pragma unroll
    for (int tile = 0; tile < 4; ++tile) {
        int tok = wtok + tile*16 + n;
        float nrm = 0.f;
#pragma unroll
        for (int kf = 0; kf < 2; ++kf) {
            float4 p0 = z4[(size_t)tok*16 + kf*8 + q*2];
            float4 p1 = z4[(size_t)tok*16 + kf*8 + q*2 + 1];
            float v[8] = {p0.x,p0.y,p0.z,p0.w,p1.x,p1.y,p1.z,p1.w};
            bf16x8 hv, lv;
#pragma unroll
            for (int j = 0; j < 8; ++j) {
                float f = v[j];
                nrm = fmaf(f, f, nrm);
                __bf16 h = (__bf16)f;
                __bf16 l = (__bf16)(f - (float)h);
                hv[j] = h; lv[j] = l;
            }
            ah[tile][kf] = hv; al[tile][kf] = lv;
        }
        nrm += __shfl_xor(nrm, 16, 64);
        nrm += __shfl_xor(nrm, 32, 64);
        pn[tile] = nrm;
    }

    float best[16];
#pragma unroll
    for (int s = 0; s < 16; ++s) best[s] = -3.4e38f;

    // Barrier-free K-loop: 16 chunks of 16 codes, B-frags straight from cbF.
    const int c0 = w * 16;
    const __bf16* ph = cbF + (size_t)c0 * 1024 + lane * 8;
    const __bf16* pl = ph + 65536;
    const float* cnp = cn2 + c0*16 + n;
#pragma unroll 2
    for (int cc = 0; cc < 16; ++cc) {
        bf16x8 bh0 = *(const bf16x8*)(ph);
        bf16x8 bh1 = *(const bf16x8*)(ph + 512);
        bf16x8 bl0 = *(const bf16x8*)(pl);
        bf16x8 bl1 = *(const bf16x8*)(pl + 512);
        const float cnv = *cnp;
        const u32 codebits = (u32)((c0 + cc)*16 + n);
#pragma unroll
        for (int tile = 0; tile < 4; ++tile) {
            f32x4 acc = {cnv, cnv, cnv, cnv};
            acc = __builtin_amdgcn_mfma_f32_16x16x32_bf16(ah[tile][0], bh0, acc, 0, 0, 0);
            acc = __builtin_amdgcn_mfma_f32_16x16x32_bf16(ah[tile][1], bh1, acc, 0, 0, 0);
            acc = __builtin_amdgcn_mfma_f32_16x16x32_bf16(al[tile][0], bh0, acc, 0, 0, 0);
            acc = __builtin_amdgcn_mfma_f32_16x16x32_bf16(al[tile][1], bh1, acc, 0, 0, 0);
            acc = __builtin_amdgcn_mfma_f32_16x16x32_bf16(ah[tile][0], bl0, acc, 0, 0, 0);
            acc = __builtin_amdgcn_mfma_f32_16x16x32_bf16(ah[tile][1], bl1, acc, 0, 0, 0);
#pragma unroll
            for (int r = 0; r < 4; ++r) {
                float packed = __uint_as_float((__float_as_uint(acc[r]) & 0xFFFFFC00u) | codebits);
                best[tile*4 + r] = fmaxf(best[tile*4 + r], packed);
            }
        }
        ph += 1024; pl += 1024; cnp += 16;
    }

    // n-reduce each slot; n==0 lanes publish this wave's 64 token-winners.
#pragma unroll
    for (int s = 0; s < 16; ++s) {
        float bs = best[s];
#pragma unroll
        for (int m = 8; m >= 1; m >>= 1)
            bs = fmaxf(bs, __shfl_xor(bs, m, 64));
        if (n == 0) lmerge[w*64 + (s >> 2)*16 + q*4 + (s & 3)] = bs;
    }
    __syncthreads();                                  // the ONLY compute barrier

    // Wave w finalizes its 16 tokens [wtok+w*16, +16): merge 4 quarters,
    // counts atomics, SSE from scores (d = ||z||^2 - 2*score).
    float pnw = (w == 0) ? pn[0] : (w == 1) ? pn[1] : (w == 2) ? pn[2] : pn[3];
    int myid = 0;
    if (lane < 16) {
        int ti = w*16 + lane;
        float m0 = lmerge[ti], m1 = lmerge[64 + ti], m2 = lmerge[128 + ti], m3 = lmerge[192 + ti];
        float bw = fmaxf(fmaxf(m0, m1), fmaxf(m2, m3));
        u32 bits = __float_as_uint(bw);
        myid = (int)(bits & 0x3FFu);
        float sc = __uint_as_float(bits & 0xFFFFFC00u);
        atomicAdd(&counts[myid], 1u);
        float sacc = fmaf(-2.f, sc, pnw);            // lane<16: pnw holds token w*16+lane's norm
        sacc += __shfl_down(sacc, 8, 64);
        sacc += __shfl_down(sacc, 4, 64);
        sacc += __shfl_down(sacc, 2, 64);
        sacc += __shfl_down(sacc, 1, 64);
        if (lane == 0) atomicAdd(sse, sacc);
    }

    // z_q write: 16 tokens/wave, readlane id -> independent coalesced row copies.
    const size_t obase = 1 + (size_t)(wtok + w*16) * DIM;
#pragma unroll
    for (int i = 0; i < 16; ++i) {
        int id = __shfl(myid, i, 64);                // compile-time lane -> v_readlane
        float qv = cb[(size_t)id * DIM + lane];
        out[obase + (size_t)i * DIM + lane] = qv;
    }

    // Last-block finalize (device-scope handshake; all cross-block reads atomic).
    __threadfence();
    if (t == 0) lastflag = (atomicAdd(done, 1u) == (u32)(gridDim.x - 1)) ? 1u : 0u;
    __syncthreads();
    if (lastflag) {
        float acc = 0.f;
#pragma unroll
        for (int i = 0; i < 4; ++i) {
            u32 cv = atomicAdd(&counts[t + 256*i], 0u);      // coherent read
            float p = (float)cv * (1.0f / 131072.0f);
            acc += p * logf(p + 1e-10f);
        }
#pragma unroll
        for (int off = 32; off; off >>= 1) acc += __shfl_down(acc, off, 64);
        if ((t & 63) == 0) fred[t >> 6] = acc;
        __syncthreads();
        if (t == 0) {
            float H = -((fred[0] + fred[1]) + (fred[2] + fred[3]));
            float sv = atomicAdd(sse, 0.0f);                 // coherent read
            out[0] = 1.25f * sv * (1.0f / 8388608.0f);       // (1+BETA)*MSE
            out[8388609] = expf(H);
        }
    }
}

extern "C" void kernel_launch(void* const* d_in, const int* in_sizes, int n_in,
                              void* d_out, int out_size, void* d_ws, size_t ws_size,
                              hipStream_t stream) {
    const float* z  = (const float*)d_in[0];
    const float* cb = (const float*)d_in[1];
    float* out = (float*)d_out;
    char* ws = (char*)d_ws;
    float*    cn2    = (float*)(ws + WS_CN2);
    __bf16*   cbF    = (__bf16*)(ws + WS_CBF);
    unsigned* counts = (unsigned*)(ws + WS_COUNTS);
    float*    sse    = (float*)(ws + WS_SSE);
    unsigned* done   = (unsigned*)(ws + WS_DONE);

    prep_kernel<<<4, 256, 0, stream>>>(cb, cn2, cbF, counts, sse, done);
    fused_kernel<<<N_TOK/64, 256, 0, stream>>>(z, cbF, cn2, cb, out, counts, sse, done);
}

// Round 7
// 250.108 us; speedup vs baseline: 1.5529x; 1.5529x over previous
//
#include <hip/hip_runtime.h>
#include <cfloat>
#include <cmath>

#define N_TOK (32*4096)                 // 131072 tokens
#define DIM   64
#define N_E   1024

typedef __attribute__((ext_vector_type(8))) __bf16 bf16x8;
typedef __attribute__((ext_vector_type(4))) float  f32x4;
typedef unsigned int u32;

// ws layout (bytes)
#define WS_CN2    0u                    // 1024 f32 (-0.5*||e||^2)           (4 KB)
#define WS_CBF    4096u                 // per-128-block fragment bf16 hi+lo (256 KB)
#define WS_COUNTS 266240u               // 1024 u32                          (4 KB)
#define WS_SSEA   270336u               // 64 f32 partial SSE cells
#define WS_DONE   270592u               // 1 u32

// async global->LDS, 16 B per lane; LDS dest must be wave-uniform base + lane*16
__device__ __forceinline__ void async_cp16(const void* g, void* l) {
    __builtin_amdgcn_global_load_lds((const __attribute__((address_space(1))) u32*)g,
                                     (__attribute__((address_space(3))) u32*)l, 16, 0, 0);
}

// Codebook -> MFMA B-fragment order (bf16 hi/lo), round-5 layout:
//   cbF[cblk*16384 + plane*8192 + ch*1024 + kf*512 + (q*16+n)*8 + j]
//     = plane_of( e[cblk*128 + ch*16 + n][kf*32 + q*8 + j] )
// 32 blocks x 256 threads; thread = (code, oct): coalesced 32 B load, 2x16 B stores.
__global__ __launch_bounds__(256) void prep_kernel(const float* __restrict__ cb,
        float* __restrict__ cn2, __bf16* __restrict__ cbF,
        unsigned* __restrict__ counts, float* __restrict__ ssea, unsigned* __restrict__ done) {
    const int t = threadIdx.x;
    const int k = blockIdx.x * 32 + (t >> 3);        // code 0..1023
    const int oct = t & 7;                           // 8 floats per oct
    if (t < 32) counts[blockIdx.x * 32 + t] = 0u;
    if (blockIdx.x == 0 && t < 64) ssea[t] = 0.f;
    if (blockIdx.x == 0 && t == 0) *done = 0u;

    const float4 a = *(const float4*)(cb + (size_t)k * DIM + oct * 8);
    const float4 b = *(const float4*)(cb + (size_t)k * DIM + oct * 8 + 4);
    float v[8] = {a.x,a.y,a.z,a.w,b.x,b.y,b.z,b.w};
    bf16x8 hv, lv;
    float nrm = 0.f;
#pragma unroll
    for (int j = 0; j < 8; ++j) {
        float f = v[j];
        nrm = fmaf(f, f, nrm);
        __bf16 h = (__bf16)f;
        __bf16 l = (__bf16)(f - (float)h);
        hv[j] = h; lv[j] = l;
    }
    const int cblk = k >> 7, local = k & 127;
    const int ch = local >> 4, n = local & 15;
    const int kf = oct >> 2, q = oct & 3;
    __bf16* base = cbF + (size_t)cblk * 16384 + ch * 1024 + kf * 512 + q * 128 + n * 8;
    *(bf16x8*)(base) = hv;
    *(bf16x8*)(base + 8192) = lv;
    // norm reduce over the 8 octs of this code (consecutive lanes)
    nrm += __shfl_xor(nrm, 1, 64);
    nrm += __shfl_xor(nrm, 2, 64);
    nrm += __shfl_xor(nrm, 4, 64);
    if (oct == 0) cn2[k] = -0.5f * nrm;
}

// Fused: per-wave 32 tokens x all 1024 codes (LDS-staged), argmax(z.e - ||e||^2/2),
// counts/SSE-from-scores/z_q writes per wave, last-block finalize.
__global__ __launch_bounds__(256, 4) void fused_kernel(const float* __restrict__ z,
        const __bf16* __restrict__ cbF, const float* __restrict__ cn2,
        const float* __restrict__ cb, float* __restrict__ out,
        unsigned* __restrict__ counts, float* __restrict__ ssea, unsigned* __restrict__ done) {
    __shared__ __bf16 lbuf[16384];                   // 32 KB staging, fragment-ordered
    __shared__ float  lcn[128];
    __shared__ int    lwin[128];                     // 4 waves x 32 winner ids
    __shared__ float  fred[4];
    __shared__ u32    lastflag;
    const int t    = threadIdx.x;
    const int lane = t & 63;
    const int w    = t >> 6;
    const int n    = lane & 15;                      // MFMA col / code-in-chunk
    const int q    = lane >> 4;                      // k-octet selector
    const int wtok = blockIdx.x * 128 + w * 32;      // wave's 32 contiguous tokens

    // A fragments: 2 tiles x 2 K-halves, bf16 hi/lo; pn[tile] = exact fp32 ||z||^2.
    bf16x8 ah[2][2], al[2][2];
    float pn[2];
    const float4* z4 = (const float4*)z;
#pragma unroll
    for (int tile = 0; tile < 2; ++tile) {
        int tok = wtok + tile*16 + n;
        float nrm = 0.f;
#pragma unroll
        for (int kf = 0; kf < 2; ++kf) {
            float4 p0 = z4[(size_t)tok*16 + kf*8 + q*2];
            float4 p1 = z4[(size_t)tok*16 + kf*8 + q*2 + 1];
            float v[8] = {p0.x,p0.y,p0.z,p0.w,p1.x,p1.y,p1.z,p1.w};
            bf16x8 hv, lv;
#pragma unroll
            for (int j = 0; j < 8; ++j) {
                float f = v[j];
                nrm = fmaf(f, f, nrm);
                __bf16 h = (__bf16)f;
                __bf16 l = (__bf16)(f - (float)h);
                hv[j] = h; lv[j] = l;
            }
            ah[tile][kf] = hv; al[tile][kf] = lv;
        }
        nrm += __shfl_xor(nrm, 16, 64);
        nrm += __shfl_xor(nrm, 32, 64);
        pn[tile] = nrm;
    }

    float best[8];
#pragma unroll
    for (int s = 0; s < 8; ++s) best[s] = -3.4e38f;

    for (int cblk = 0; cblk < 8; ++cblk) {
        __syncthreads();                             // protect lbuf from prev reads
        const __bf16* gsrc = cbF + (size_t)cblk * 16384;
#pragma unroll
        for (int i = 0; i < 8; ++i) {
            int off = (i*256 + t) * 16;              // bytes; lane-linear per wave
            async_cp16((const char*)gsrc + off, (char*)lbuf + off);
        }
        if (t < 128) lcn[t] = cn2[cblk*128 + t];
        __syncthreads();                             // drains vmcnt -> LDS ready

#pragma unroll 2
        for (int ch = 0; ch < 8; ++ch) {
            const int fb = ch*1024 + lane*8;         // conflict-free: lane*16 B
            bf16x8 bh0 = *(const bf16x8*)(lbuf + fb);
            bf16x8 bh1 = *(const bf16x8*)(lbuf + fb + 512);
            bf16x8 bl0 = *(const bf16x8*)(lbuf + fb + 8192);
            bf16x8 bl1 = *(const bf16x8*)(lbuf + fb + 8704);
            const float cnv = lcn[ch*16 + n];
            const u32 codebits = (u32)(cblk*128 + ch*16 + n);
#pragma unroll
            for (int tile = 0; tile < 2; ++tile) {
                f32x4 acc = {cnv, cnv, cnv, cnv};
                acc = __builtin_amdgcn_mfma_f32_16x16x32_bf16(ah[tile][0], bh0, acc, 0, 0, 0);
                acc = __builtin_amdgcn_mfma_f32_16x16x32_bf16(ah[tile][1], bh1, acc, 0, 0, 0);
                acc = __builtin_amdgcn_mfma_f32_16x16x32_bf16(al[tile][0], bh0, acc, 0, 0, 0);
                acc = __builtin_amdgcn_mfma_f32_16x16x32_bf16(al[tile][1], bh1, acc, 0, 0, 0);
                acc = __builtin_amdgcn_mfma_f32_16x16x32_bf16(ah[tile][0], bl0, acc, 0, 0, 0);
                acc = __builtin_amdgcn_mfma_f32_16x16x32_bf16(ah[tile][1], bl1, acc, 0, 0, 0);
#pragma unroll
                for (int r = 0; r < 4; ++r) {
                    float packed = __uint_as_float((__float_as_uint(acc[r]) & 0xFFFFFC00u) | codebits);
                    best[tile*4 + r] = fmaxf(best[tile*4 + r], packed);
                }
            }
        }
    }

    // Per-wave epilogue, no barriers: n-reduce each slot, publish winners,
    // counts atomics + SSE (d = ||z||^2 - 2*score) on n==0 lanes.
    float sse_acc = 0.f;
#pragma unroll
    for (int s = 0; s < 8; ++s) {
        float bs = best[s];
#pragma unroll
        for (int m = 8; m >= 1; m >>= 1)
            bs = fmaxf(bs, __shfl_xor(bs, m, 64));
        u32 bits = __float_as_uint(bs);
        int id = (int)(bits & 0x3FFu);
        float sc = __uint_as_float(bits & 0xFFFFFC00u);
        float nrm = __shfl(pn[s >> 2], (q << 2) | (s & 3), 64);  // token's exact norm
        if (n == 0) {
            lwin[w*32 + (s >> 2)*16 + q*4 + (s & 3)] = id;
            atomicAdd(&counts[id], 1u);
            sse_acc += fmaf(-2.f, sc, nrm);
        }
    }
    sse_acc += __shfl_xor(sse_acc, 16, 64);
    sse_acc += __shfl_xor(sse_acc, 32, 64);
    if (lane == 0) atomicAdd(&ssea[(blockIdx.x*4 + w) & 63], sse_acc);

    // z_q write: wave's 32 tokens; id from per-wave LDS (uniform addr -> broadcast),
    // independent coalesced 256-B row copies, unroll 8 for bounded MLP.
    const size_t obase = 1 + (size_t)wtok * DIM;
#pragma unroll 8
    for (int i = 0; i < 32; ++i) {
        int id = lwin[w*32 + i];
        float qv = cb[(size_t)id * DIM + lane];
        out[obase + (size_t)i * DIM + lane] = qv;
    }

    // Last-block finalize (device-scope handshake; cross-block reads via atomics).
    __threadfence();
    if (t == 0) lastflag = (atomicAdd(done, 1u) == (u32)(gridDim.x - 1)) ? 1u : 0u;
    __syncthreads();
    if (lastflag) {
        float acc = 0.f;
#pragma unroll
        for (int i = 0; i < 4; ++i) {
            u32 cv = atomicAdd(&counts[t + 256*i], 0u);      // coherent read
            float p = (float)cv * (1.0f / 131072.0f);
            acc += p * logf(p + 1e-10f);
        }
#pragma unroll
        for (int off = 32; off; off >>= 1) acc += __shfl_down(acc, off, 64);
        if ((t & 63) == 0) fred[t >> 6] = acc;
        float sv = (t < 64) ? atomicAdd(&ssea[t], 0.0f) : 0.f;   // coherent read
#pragma unroll
        for (int off = 32; off; off >>= 1) sv += __shfl_down(sv, off, 64);
        __syncthreads();
        if (t == 0) {
            float H = -((fred[0] + fred[1]) + (fred[2] + fred[3]));
            out[0] = 1.25f * sv * (1.0f / 8388608.0f);       // (1+BETA)*MSE
            out[8388609] = expf(H);
        }
    }
}

extern "C" void kernel_launch(void* const* d_in, const int* in_sizes, int n_in,
                              void* d_out, int out_size, void* d_ws, size_t ws_size,
                              hipStream_t stream) {
    const float* z  = (const float*)d_in[0];
    const float* cb = (const float*)d_in[1];
    float* out = (float*)d_out;
    char* ws = (char*)d_ws;
    float*    cn2    = (float*)(ws + WS_CN2);
    __bf16*   cbF    = (__bf16*)(ws + WS_CBF);
    unsigned* counts = (unsigned*)(ws + WS_COUNTS);
    float*    ssea   = (float*)(ws + WS_SSEA);
    unsigned* done   = (unsigned*)(ws + WS_DONE);

    prep_kernel<<<32, 256, 0, stream>>>(cb, cn2, cbF, counts, ssea, done);
    fused_kernel<<<N_TOK/128, 256, 0, stream>>>(z, cbF, cn2, cb, out, counts, ssea, done);
}

// Round 8
// 136.118 us; speedup vs baseline: 2.8534x; 1.8374x over previous
//
#include <hip/hip_runtime.h>
#include <cfloat>
#include <cmath>

#define N_TOK (32*4096)                 // 131072 tokens
#define DIM   64
#define N_E   1024

typedef __attribute__((ext_vector_type(8))) __bf16 bf16x8;
typedef __attribute__((ext_vector_type(4))) float  f32x4;
typedef unsigned int u32;

// ws layout (bytes)
#define WS_CN2    0u                    // 1024 f32 (-0.5*||e||^2)           (4 KB)
#define WS_CBF    4096u                 // fragment-ordered bf16 hi+lo       (256 KB)
#define WS_GIDX   266240u               // 131072 int winner ids             (512 KB)
#define WS_COUNTS 790528u               // 1024 u32                          (4 KB)
#define WS_SSEA   794624u               // 64 f32 partial SSE cells
#define WS_DONE   794880u               // 1 u32

// async global->LDS, 16 B per lane; LDS dest must be wave-uniform base + lane*16
__device__ __forceinline__ void async_cp16(const void* g, void* l) {
    __builtin_amdgcn_global_load_lds((const __attribute__((address_space(1))) u32*)g,
                                     (__attribute__((address_space(3))) u32*)l, 16, 0, 0);
}

// Codebook -> MFMA B-fragment order (bf16 hi/lo), round-5 layout:
//   cbF[cblk*16384 + plane*8192 + ch*1024 + kf*512 + (q*16+n)*8 + j]
// 32 blocks x 256 threads; thread = (code, oct): coalesced loads/stores.
__global__ __launch_bounds__(256) void prep_kernel(const float* __restrict__ cb,
        float* __restrict__ cn2, __bf16* __restrict__ cbF,
        unsigned* __restrict__ counts, float* __restrict__ ssea, unsigned* __restrict__ done) {
    const int t = threadIdx.x;
    const int k = blockIdx.x * 32 + (t >> 3);        // code 0..1023
    const int oct = t & 7;
    if (t < 32) counts[blockIdx.x * 32 + t] = 0u;
    if (blockIdx.x == 0 && t < 64) ssea[t] = 0.f;
    if (blockIdx.x == 0 && t == 0) *done = 0u;

    const float4 a = *(const float4*)(cb + (size_t)k * DIM + oct * 8);
    const float4 b = *(const float4*)(cb + (size_t)k * DIM + oct * 8 + 4);
    float v[8] = {a.x,a.y,a.z,a.w,b.x,b.y,b.z,b.w};
    bf16x8 hv, lv;
    float nrm = 0.f;
#pragma unroll
    for (int j = 0; j < 8; ++j) {
        float f = v[j];
        nrm = fmaf(f, f, nrm);
        __bf16 h = (__bf16)f;
        __bf16 l = (__bf16)(f - (float)h);
        hv[j] = h; lv[j] = l;
    }
    const int cblk = k >> 7, local = k & 127;
    const int ch = local >> 4, n = local & 15;
    const int kf = oct >> 2, q = oct & 3;
    __bf16* base = cbF + (size_t)cblk * 16384 + ch * 1024 + kf * 512 + q * 128 + n * 8;
    *(bf16x8*)(base) = hv;
    *(bf16x8*)(base + 8192) = lv;
    nrm += __shfl_xor(nrm, 1, 64);
    nrm += __shfl_xor(nrm, 2, 64);
    nrm += __shfl_xor(nrm, 4, 64);
    if (oct == 0) cn2[k] = -0.5f * nrm;
}

// Round-5 fused shape (proven 84us): 512 blocks, 64 tokens/wave, all 1024 codes
// LDS-staged. De-atomicized epilogue: ids -> plain store to gidx, SSE -> 64 cells.
__global__ __launch_bounds__(256, 2) void fused_kernel(const float* __restrict__ z,
        const __bf16* __restrict__ cbF, const float* __restrict__ cn2,
        const float* __restrict__ cb, float* __restrict__ out,
        int* __restrict__ gidx, float* __restrict__ ssea) {
    __shared__ __bf16 lbuf[16384];                   // 32 KB, fragment-ordered
    __shared__ float  lcn[128];
    __shared__ int    lidx[256];
    const int t    = threadIdx.x;
    const int lane = t & 63;
    const int w    = t >> 6;
    const int n    = lane & 15;                      // MFMA col / code-in-chunk
    const int q    = lane >> 4;                      // k-octet selector
    const int wtok = blockIdx.x * 256 + w * 64;

    // A fragments (64 tokens/wave as 4 tiles x 2 K-halves), bf16 hi/lo in regs.
    bf16x8 ah[4][2], al[4][2];
    float pn[4];
    const float4* z4 = (const float4*)z;
#pragma unroll
    for (int tile = 0; tile < 4; ++tile) {
        int tok = wtok + tile*16 + n;
        float nrm = 0.f;
#pragma unroll
        for (int kf = 0; kf < 2; ++kf) {
            float4 p0 = z4[(size_t)tok*16 + kf*8 + q*2];
            float4 p1 = z4[(size_t)tok*16 + kf*8 + q*2 + 1];
            float v[8] = {p0.x,p0.y,p0.z,p0.w,p1.x,p1.y,p1.z,p1.w};
            bf16x8 hv, lv;
#pragma unroll
            for (int j = 0; j < 8; ++j) {
                float f = v[j];
                nrm = fmaf(f, f, nrm);
                __bf16 h = (__bf16)f;
                __bf16 l = (__bf16)(f - (float)h);
                hv[j] = h; lv[j] = l;
            }
            ah[tile][kf] = hv; al[tile][kf] = lv;
        }
        nrm += __shfl_xor(nrm, 16, 64);
        nrm += __shfl_xor(nrm, 32, 64);
        pn[tile] = nrm;
    }

    float best[16];
#pragma unroll
    for (int s = 0; s < 16; ++s) best[s] = -3.4e38f;

    for (int cblk = 0; cblk < 8; ++cblk) {
        __syncthreads();
        const __bf16* gsrc = cbF + (size_t)cblk * 16384;
#pragma unroll
        for (int i = 0; i < 8; ++i) {
            int off = (i*256 + t) * 16;              // bytes; lane-linear per wave
            async_cp16((const char*)gsrc + off, (char*)lbuf + off);
        }
        if (t < 128) lcn[t] = cn2[cblk*128 + t];
        __syncthreads();                             // drains vmcnt -> LDS ready

#pragma unroll 2
        for (int ch = 0; ch < 8; ++ch) {
            const int fb = ch*1024 + lane*8;         // conflict-free: lane*16 B
            bf16x8 bh0 = *(const bf16x8*)(lbuf + fb);
            bf16x8 bh1 = *(const bf16x8*)(lbuf + fb + 512);
            bf16x8 bl0 = *(const bf16x8*)(lbuf + fb + 8192);
            bf16x8 bl1 = *(const bf16x8*)(lbuf + fb + 8704);
            const float cnv = lcn[ch*16 + n];
            const u32 codebits = (u32)(cblk*128 + ch*16 + n);
#pragma unroll
            for (int tile = 0; tile < 4; ++tile) {
                f32x4 acc = {cnv, cnv, cnv, cnv};
                acc = __builtin_amdgcn_mfma_f32_16x16x32_bf16(ah[tile][0], bh0, acc, 0, 0, 0);
                acc = __builtin_amdgcn_mfma_f32_16x16x32_bf16(ah[tile][1], bh1, acc, 0, 0, 0);
                acc = __builtin_amdgcn_mfma_f32_16x16x32_bf16(al[tile][0], bh0, acc, 0, 0, 0);
                acc = __builtin_amdgcn_mfma_f32_16x16x32_bf16(al[tile][1], bh1, acc, 0, 0, 0);
                acc = __builtin_amdgcn_mfma_f32_16x16x32_bf16(ah[tile][0], bl0, acc, 0, 0, 0);
                acc = __builtin_amdgcn_mfma_f32_16x16x32_bf16(ah[tile][1], bl1, acc, 0, 0, 0);
#pragma unroll
                for (int r = 0; r < 4; ++r) {
                    float packed = __uint_as_float((__float_as_uint(acc[r]) & 0xFFFFFC00u) | codebits);
                    best[tile*4 + r] = fmaxf(best[tile*4 + r], packed);
                }
            }
        }
    }

    // Winner reduce; NO counts atomics — ids go to LDS then plain coalesced store.
    float sse_acc = 0.f;
#pragma unroll
    for (int s = 0; s < 16; ++s) {
        float bs = best[s];
#pragma unroll
        for (int m = 8; m >= 1; m >>= 1)
            bs = fmaxf(bs, __shfl_xor(bs, m, 64));
        u32 bits = __float_as_uint(bs);
        int id = (int)(bits & 0x3FFu);
        float sc = __uint_as_float(bits & 0xFFFFFC00u);
        float nrm = __shfl(pn[s >> 2], (q << 2) | (s & 3), 64);
        if (n == 0) {
            lidx[w*64 + (s >> 2)*16 + q*4 + (s & 3)] = id;
            sse_acc += fmaf(-2.f, sc, nrm);          // d = ||z||^2 - 2*score
        }
    }
    sse_acc += __shfl_xor(sse_acc, 16, 64);
    sse_acc += __shfl_xor(sse_acc, 32, 64);
    if (lane == 0) atomicAdd(&ssea[(blockIdx.x*4 + w) & 63], sse_acc);

    int myid = lidx[w*64 + lane];                    // wave-local LDS, no barrier needed
    gidx[wtok + lane] = myid;                        // coalesced id publish

    // z_q write: wave's 64 tokens, readlane id -> independent coalesced row copies.
    const size_t obase = 1 + (size_t)wtok * DIM;
#pragma unroll
    for (int i = 0; i < 64; ++i) {
        int id = __shfl(myid, i, 64);                // compile-time lane -> v_readlane
        float qv = cb[(size_t)id * DIM + lane];
        out[obase + (size_t)i * DIM + lane] = qv;
    }
}

// Histogram from gidx via per-block LDS counts (LDS atomics), then 32 spread
// global adds per cell; last block computes entropy + loss.
__global__ __launch_bounds__(256) void hist_kernel(const int* __restrict__ gidx,
        unsigned* __restrict__ counts, const float* __restrict__ ssea,
        unsigned* __restrict__ done, float* __restrict__ out) {
    __shared__ unsigned hist[1024];
    __shared__ float fred[4];
    __shared__ u32 lastflag;
    const int t = threadIdx.x;
#pragma unroll
    for (int i = 0; i < 4; ++i) hist[t + 256*i] = 0u;
    __syncthreads();
    const int base = blockIdx.x * 4096;
#pragma unroll
    for (int i = 0; i < 16; ++i) {
        int id = gidx[base + i*256 + t];
        atomicAdd(&hist[id], 1u);
    }
    __syncthreads();
#pragma unroll
    for (int i = 0; i < 4; ++i) {
        unsigned v = hist[t + 256*i];
        if (v) atomicAdd(&counts[t + 256*i], v);
    }
    __threadfence();
    __syncthreads();
    if (t == 0) lastflag = (atomicAdd(done, 1u) == 31u) ? 1u : 0u;
    __syncthreads();
    if (lastflag) {
        float acc = 0.f;
#pragma unroll
        for (int i = 0; i < 4; ++i) {
            u32 cv = atomicAdd(&counts[t + 256*i], 0u);      // coherent read
            float p = (float)cv * (1.0f / 131072.0f);
            acc += p * logf(p + 1e-10f);
        }
#pragma unroll
        for (int off = 32; off; off >>= 1) acc += __shfl_down(acc, off, 64);
        if ((t & 63) == 0) fred[t >> 6] = acc;
        float sv = (t < 64) ? ssea[t] : 0.f;                 // prior-dispatch data
#pragma unroll
        for (int off = 32; off; off >>= 1) sv += __shfl_down(sv, off, 64);
        __syncthreads();
        if (t == 0) {
            float H = -((fred[0] + fred[1]) + (fred[2] + fred[3]));
            out[0] = 1.25f * sv * (1.0f / 8388608.0f);       // (1+BETA)*MSE
            out[8388609] = expf(H);
        }
    }
}

extern "C" void kernel_launch(void* const* d_in, const int* in_sizes, int n_in,
                              void* d_out, int out_size, void* d_ws, size_t ws_size,
                              hipStream_t stream) {
    const float* z  = (const float*)d_in[0];
    const float* cb = (const float*)d_in[1];
    float* out = (float*)d_out;
    char* ws = (char*)d_ws;
    float*    cn2    = (float*)(ws + WS_CN2);
    __bf16*   cbF    = (__bf16*)(ws + WS_CBF);
    int*      gidx   = (int*)(ws + WS_GIDX);
    unsigned* counts = (unsigned*)(ws + WS_COUNTS);
    float*    ssea   = (float*)(ws + WS_SSEA);
    unsigned* done   = (unsigned*)(ws + WS_DONE);

    prep_kernel<<<32, 256, 0, stream>>>(cb, cn2, cbF, counts, ssea, done);
    fused_kernel<<<N_TOK/256, 256, 0, stream>>>(z, cbF, cn2, cb, out, gidx, ssea);
    hist_kernel<<<32, 256, 0, stream>>>(gidx, counts, ssea, done, out);
}